// Round 10
// baseline (257.945 us; speedup 1.0000x reference)
//
#include <hip/hip_runtime.h>
#include <hip/hip_bf16.h>

constexpr int NN = 50000;   // nodes
constexpr int NE = 800000;  // edges
constexpr int NBUCK = (NN + 255) / 256;   // 196 buckets of 256 nodes
constexpr int P1B = (NE + 4095) / 4096;   // 196 pass-1 blocks
constexpr int BCAP = 6144;                // bucket capacity (mean 4082, sigma 64)

// k_prep blockIdx ranges: [pass1 | convx(grid-stride) | wpack1 | wpack2]
constexpr int PREP_CONVX_B = 1563;                   // grid-stride: 4 items/thread
constexpr int PREP_WP1 = (384 * 128 + 255) / 256;    // 192
constexpr int PREP_WP2 = (128 * 96 + 255) / 256;     // 48
constexpr int PREP_TOT = P1B + PREP_CONVX_B + PREP_WP1 + PREP_WP2;

constexpr int AGG_BLOCKS = 2048;          // 8192 waves grid-stride (agg2)
constexpr int AGG_WAVES = AGG_BLOCKS * 4;

typedef __attribute__((ext_vector_type(8))) short short8;
typedef __attribute__((ext_vector_type(4))) float float4v;
typedef __attribute__((ext_vector_type(2))) float floatx2;

__device__ __forceinline__ unsigned short f2bf(float f) {
    unsigned int u = __builtin_bit_cast(unsigned int, f);
    u += 0x7FFFu + ((u >> 16) & 1u);   // round-to-nearest-even
    return (unsigned short)(u >> 16);
}
__device__ __forceinline__ unsigned int pack2bf(float lo, float hi) {
    return (unsigned int)f2bf(lo) | ((unsigned int)f2bf(hi) << 16);
}

// ===========================================================================
// Fused preprocessing (R6-verified): CSR pass1 (block-local counting sort ->
// coalesced bucket writes) | convx (bf16+fp8, grid-stride) | wpack1 | wpack2.
// bin_counter zeroed by memset node before this kernel.
// ===========================================================================
__global__ __launch_bounds__(256) void k_prep(
    const float* __restrict__ x, unsigned short* __restrict__ Xb,
    unsigned char* __restrict__ Xq,
    const float* __restrict__ W1flat, const float* __restrict__ root1,
    unsigned short* __restrict__ Wp,
    const float* __restrict__ W2, const float* __restrict__ root2,
    unsigned short* __restrict__ Wp2,
    const int* __restrict__ esrc, const int* __restrict__ edst,
    const float* __restrict__ u,
    int* __restrict__ bin_counter, uint2* __restrict__ epack8)
{
    int b = blockIdx.x, t = threadIdx.x;
    if (b < P1B) {
        __shared__ int cnt[256];     // per-bin block-local histogram
        __shared__ int base[256];    // global reservation base (slot in bucket)
        __shared__ int off[256];     // inclusive scan of cnt
        __shared__ int pos[256];     // per-bin running counter
        __shared__ uint2 se[4096];   // staged edges, sorted by bin (32 KB)
        __shared__ int sa[4096];     // global destination slot (16 KB)
        int e0 = b * 4096;
        int e1 = min(e0 + 4096, NE);
        cnt[t] = 0;
        pos[t] = 0;
        __syncthreads();
        for (int e = e0 + t; e < e1; e += 256)
            atomicAdd(&cnt[edst[e] >> 8], 1);
        __syncthreads();
        base[t] = (t < NBUCK && cnt[t] > 0) ? atomicAdd(&bin_counter[t], cnt[t]) : 0;
        off[t] = cnt[t];
        __syncthreads();
#pragma unroll
        for (int o = 1; o < 256; o <<= 1) {
            int add = (t >= o) ? off[t - o] : 0;
            __syncthreads();
            off[t] += add;
            __syncthreads();
        }
        for (int e = e0 + t; e < e1; e += 256) {
            int d = edst[e];
            int bin = d >> 8;
            int k = atomicAdd(&pos[bin], 1);
            int ls = off[bin] - cnt[bin] + k;   // block-local sorted slot
            int gs = base[bin] + k;             // slot within global bucket
            float uf = u[e] * 65535.0f + 0.5f;
            unsigned int u16 = (unsigned int)uf;
            if (u16 > 65535u) u16 = 65535u;
            uint2 v;
            v.x = ((unsigned int)esrc[e] << 16) | u16;
            v.y = (unsigned int)(d & 255);
            se[ls] = v;
            sa[ls] = (gs < BCAP) ? (bin * BCAP + gs) : -1;
        }
        __syncthreads();
        int ecnt = e1 - e0;
        for (int i = t; i < ecnt; i += 256) {
            int a = sa[i];
            if (a >= 0) epack8[a] = se[i];
        }
    } else if (b < P1B + PREP_CONVX_B) {
        int bb = b - P1B;
        for (int gid = bb * 256 + t; gid < NN * 32; gid += PREP_CONVX_B * 256) {
            int node = gid >> 5;
            int c = (gid & 31) * 4;
            float4 v = *(const float4*)&x[(size_t)node * 128 + c];
            uint2 o;
            o.x = pack2bf(v.x, v.y);
            o.y = pack2bf(v.z, v.w);
            *(uint2*)&Xb[(size_t)node * 128 + c] = o;
            unsigned int q8 = __builtin_amdgcn_cvt_pk_fp8_f32(v.x, v.y, 0, false);
            q8 = __builtin_amdgcn_cvt_pk_fp8_f32(v.z, v.w, q8, true);
            *(unsigned int*)&Xq[(size_t)node * 128 + c] = q8;
        }
    } else if (b < P1B + PREP_CONVX_B + PREP_WP1) {
        int o = (b - P1B - PREP_CONVX_B) * 256 + t;
        if (o < 384 * 128) {
            int j = o & 7, l = (o >> 3) & 63, fi = o >> 9;
            int nt = fi & 7, kt = fi >> 3;
            int k = kt * 32 + (l >> 4) * 8 + j;
            int n = nt * 16 + (l & 15);
            float v = (k < 256) ? W1flat[k * 128 + n] : root1[(k - 256) * 128 + n];
            Wp[o] = f2bf(v);
        }
    } else {
        int o = (b - P1B - PREP_CONVX_B - PREP_WP1) * 256 + t;
        if (o < 128 * 96) {
            int j = o & 7, l = (o >> 3) & 63, fi = o >> 9;
            int nt = fi % 6, kt = fi / 6;
            int k = kt * 32 + (l >> 4) * 8 + j;
            int c = nt * 16 + (l & 15);
            float v = (c < 64) ? W2[(c >> 5) * 4096 + k * 32 + (c & 31)]
                               : root2[k * 32 + (c - 64)];
            Wp2[o] = f2bf(v);
        }
    }
}

// ===========================================================================
// Pass 2 (1024 threads): inline bin-count scan (ebase) + per-bucket LDS
// counting sort -> rowptr + compact final spack (coalesced). [R6-verified]
// ===========================================================================
__global__ __launch_bounds__(1024) void k_pass2(
    const uint2* __restrict__ epack8, const int* __restrict__ bin_counter,
    unsigned int* __restrict__ spack, int* __restrict__ rowptr)
{
    __shared__ int bsum[256];
    __shared__ int pos[256];
    __shared__ unsigned int sorted[BCAP];
    int b = blockIdx.x, t = threadIdx.x;

    if (t < 256) bsum[t] = (t < NBUCK) ? bin_counter[t] : 0;
    __syncthreads();
#pragma unroll
    for (int off = 1; off < 256; off <<= 1) {
        int add = (t >= off && t < 256) ? bsum[t - off] : 0;
        __syncthreads();
        if (t < 256) bsum[t] += add;
        __syncthreads();
    }
    int myCnt = bin_counter[b];
    int ebase = bsum[b] - myCnt;
    int ecnt = min(myCnt, BCAP);

    if (t < 256) pos[t] = 0;
    __syncthreads();
    for (int i = t; i < ecnt; i += 1024) {
        uint2 e = epack8[(size_t)b * BCAP + i];
        atomicAdd(&pos[e.y], 1);
    }
    __syncthreads();
    int v = (t < 256) ? pos[t] : 0;
    __syncthreads();
#pragma unroll
    for (int off = 1; off < 256; off <<= 1) {
        int add = (t >= off && t < 256) ? pos[t - off] : 0;
        __syncthreads();
        if (t < 256) pos[t] += add;
        __syncthreads();
    }
    int excl = (t < 256) ? (pos[t] - v) : 0;
    int node = b * 256 + t;
    if (t < 256 && node < NN) rowptr[node] = ebase + excl;
    if (b == NBUCK - 1 && t == 0) rowptr[NN] = NE;
    __syncthreads();
    if (t < 256) pos[t] = excl;
    __syncthreads();
    for (int i = t; i < ecnt; i += 1024) {
        uint2 e = epack8[(size_t)b * BCAP + i];
        int slot = atomicAdd(&pos[e.y], 1);
        if (slot < BCAP) sorted[slot] = e.x;
    }
    __syncthreads();
    for (int i = t; i < ecnt; i += 1024)
        spack[ebase + i] = sorted[i];
}

// ===========================================================================
// FUSED layer-1 aggregation + GEMM1 + GEMM2 (256 threads, R8 frame).
// Phase 0 REWORKED: 8 lanes x 16B per edge -> 8 edges per wave-load (was 4).
//   Halves gather instruction count (transaction-issue-bound per R8/R9 PMC:
//   VALU 29%, MFMA 3%, HBM 7% — nothing busy => per-instruction cost).
// Phase 1: H = relu([As|Xb] @ Wb + b1) -> Hs (aliases As).
// Phase 2: [T2q(fp8) | T2r(fp32)] = H @ Wb2 (+b2 on root).
// ===========================================================================
__global__ __launch_bounds__(256) void gemm12_fused(
    const int* __restrict__ rowptr, const unsigned int* __restrict__ spack,
    const unsigned char* __restrict__ Xq,
    const unsigned short* __restrict__ Xb,
    const unsigned short* __restrict__ Wp,
    const float* __restrict__ bias1,
    const unsigned short* __restrict__ Wp2,
    const float* __restrict__ b2,
    unsigned char* __restrict__ T2q, float* __restrict__ T2r)
{
    __shared__ __align__(16) unsigned short As[64][264];   // 33.8 KB
    const int t = threadIdx.x;
    const int wave = t >> 6, l = t & 63;
    const int lo16 = l & 15, q = l >> 4;
    const int m0 = blockIdx.x * 64;
    const int o8 = l >> 3;        // edge slot 0..7
    const int h8 = l & 7;         // col group (16 cols each)
    const int c16 = h8 * 16;      // byte offset into 128B fp8 row

    // ---- phase 0: gather-aggregate, 16 nodes/wave, 8 edges per wave-load ----
    for (int i = 0; i < 16; i++) {
        int lr = wave * 16 + i;
        int node = m0 + lr;
        if (node >= NN) {
            if (l < 8) {
                uint4 z = make_uint4(0u, 0u, 0u, 0u);
                *(uint4*)&As[lr][c16] = z;
                *(uint4*)&As[lr][c16 + 8] = z;
                *(uint4*)&As[lr][128 + c16] = z;
                *(uint4*)&As[lr][128 + c16 + 8] = z;
            }
            continue;
        }
        int e0 = rowptr[node], e1 = rowptr[node + 1];
        float sx[16], su[16];
#pragma unroll
        for (int d = 0; d < 16; d++) { sx[d] = 0.f; su[d] = 0.f; }
        unsigned int sp0 = 0, sp1 = 0, sp2 = 0;
        uint4 g0 = make_uint4(0, 0, 0, 0), g1 = make_uint4(0, 0, 0, 0);
        if (e0 < e1) {
            int i0 = e0 + o8;      if (i0 >= e1) i0 = e1 - 1;
            int i1 = e0 + 8 + o8;  if (i1 >= e1) i1 = e1 - 1;
            int i2 = e0 + 16 + o8; if (i2 >= e1) i2 = e1 - 1;
            sp0 = spack[i0];
            sp1 = spack[i1];
            sp2 = spack[i2];
            g0 = *(const uint4*)&Xq[(size_t)(sp0 >> 16) * 128 + c16];
            g1 = *(const uint4*)&Xq[(size_t)(sp1 >> 16) * 128 + c16];
        }
        for (int e = e0; e < e1; e += 8) {
            float scale = (e + o8 < e1) ? 1.f : 0.f;
            int i3 = e + 24 + o8; if (i3 >= e1) i3 = e1 - 1;
            unsigned int sp3 = spack[i3];
            uint4 g2 = *(const uint4*)&Xq[(size_t)(sp2 >> 16) * 128 + c16];
            float uu = (float)(sp0 & 0xffffu) * (1.0f / 65535.0f);
            float us = uu * scale;
            floatx2 fa = __builtin_amdgcn_cvt_pk_f32_fp8(g0.x, false);
            floatx2 fb = __builtin_amdgcn_cvt_pk_f32_fp8(g0.x, true);
            floatx2 fc = __builtin_amdgcn_cvt_pk_f32_fp8(g0.y, false);
            floatx2 fd = __builtin_amdgcn_cvt_pk_f32_fp8(g0.y, true);
            floatx2 fe = __builtin_amdgcn_cvt_pk_f32_fp8(g0.z, false);
            floatx2 ff = __builtin_amdgcn_cvt_pk_f32_fp8(g0.z, true);
            floatx2 fg = __builtin_amdgcn_cvt_pk_f32_fp8(g0.w, false);
            floatx2 fh = __builtin_amdgcn_cvt_pk_f32_fp8(g0.w, true);
            float xv[16] = {fa[0], fa[1], fb[0], fb[1], fc[0], fc[1], fd[0], fd[1],
                            fe[0], fe[1], ff[0], ff[1], fg[0], fg[1], fh[0], fh[1]};
#pragma unroll
            for (int d = 0; d < 16; d++) {
                sx[d] += scale * xv[d];
                su[d] += us * xv[d];
            }
            sp0 = sp1; sp1 = sp2; sp2 = sp3;
            g0 = g1; g1 = g2;
        }
#pragma unroll
        for (int j = 0; j < 16; j++) {
            sx[j] += __shfl_xor(sx[j], 32);
            su[j] += __shfl_xor(su[j], 32);
            sx[j] += __shfl_xor(sx[j], 16);
            su[j] += __shfl_xor(su[j], 16);
            sx[j] += __shfl_xor(sx[j], 8);
            su[j] += __shfl_xor(su[j], 8);
        }
        if (l < 8) {   // o8 == 0 lanes hold node totals for cols h8*16..+15
            float inv = 1.0f / fmaxf((float)(e1 - e0), 1.0f);
            uint4 oA, oB, oC, oD;
            oA.x = pack2bf((sx[0] - su[0]) * inv, (sx[1] - su[1]) * inv);
            oA.y = pack2bf((sx[2] - su[2]) * inv, (sx[3] - su[3]) * inv);
            oA.z = pack2bf((sx[4] - su[4]) * inv, (sx[5] - su[5]) * inv);
            oA.w = pack2bf((sx[6] - su[6]) * inv, (sx[7] - su[7]) * inv);
            oB.x = pack2bf((sx[8] - su[8]) * inv, (sx[9] - su[9]) * inv);
            oB.y = pack2bf((sx[10] - su[10]) * inv, (sx[11] - su[11]) * inv);
            oB.z = pack2bf((sx[12] - su[12]) * inv, (sx[13] - su[13]) * inv);
            oB.w = pack2bf((sx[14] - su[14]) * inv, (sx[15] - su[15]) * inv);
            oC.x = pack2bf(su[0] * inv, su[1] * inv);
            oC.y = pack2bf(su[2] * inv, su[3] * inv);
            oC.z = pack2bf(su[4] * inv, su[5] * inv);
            oC.w = pack2bf(su[6] * inv, su[7] * inv);
            oD.x = pack2bf(su[8] * inv, su[9] * inv);
            oD.y = pack2bf(su[10] * inv, su[11] * inv);
            oD.z = pack2bf(su[12] * inv, su[13] * inv);
            oD.w = pack2bf(su[14] * inv, su[15] * inv);
            *(uint4*)&As[lr][c16] = oA;
            *(uint4*)&As[lr][c16 + 8] = oB;
            *(uint4*)&As[lr][128 + c16] = oC;
            *(uint4*)&As[lr][128 + c16 + 8] = oD;
        }
    }
    __syncthreads();

    // ---- phase 1 ----
    short8 bf[12][2];
#pragma unroll
    for (int kt = 0; kt < 12; kt++)
#pragma unroll
        for (int nl = 0; nl < 2; nl++)
            bf[kt][nl] = *(const short8*)&Wp[((size_t)(kt * 8 + wave * 2 + nl)) * 512 + l * 8];

    float4v acc[4][2];
#pragma unroll
    for (int mt = 0; mt < 4; mt++) {
        acc[mt][0] = (float4v)0.f;
        acc[mt][1] = (float4v)0.f;
    }

    int rowsg[4];
#pragma unroll
    for (int mt = 0; mt < 4; mt++) {
        int r = m0 + mt * 16 + lo16;
        rowsg[mt] = (r < NN) ? r : (NN - 1);  // clamp (Xb path); stores predicated
    }

#pragma unroll
    for (int kt = 0; kt < 12; kt++) {
#pragma unroll
        for (int mt = 0; mt < 4; mt++) {
            short8 af;
            if (kt < 8)
                af = *(const short8*)&As[mt * 16 + lo16][kt * 32 + q * 8];
            else
                af = *(const short8*)&Xb[(size_t)rowsg[mt] * 128 + (kt - 8) * 32 + q * 8];
            acc[mt][0] = __builtin_amdgcn_mfma_f32_16x16x32_bf16(af, bf[kt][0], acc[mt][0], 0, 0, 0);
            acc[mt][1] = __builtin_amdgcn_mfma_f32_16x16x32_bf16(af, bf[kt][1], acc[mt][1], 0, 0, 0);
        }
    }
    __syncthreads();   // all waves done reading As; Hs aliases it below

    unsigned short (*Hs)[136] = (unsigned short (*)[136])&As[0][0];  // 17.4 KB
    const int c0 = wave * 32;
    float b0 = bias1[c0 + lo16];
    float b1v = bias1[c0 + 16 + lo16];
#pragma unroll
    for (int mt = 0; mt < 4; mt++) {
#pragma unroll
        for (int reg = 0; reg < 4; reg++) {
            int lr = mt * 16 + q * 4 + reg;   // local row in tile
            Hs[lr][c0 + lo16] = f2bf(fmaxf(acc[mt][0][reg] + b0, 0.f));
            Hs[lr][c0 + 16 + lo16] = f2bf(fmaxf(acc[mt][1][reg] + b1v, 0.f));
        }
    }
    __syncthreads();

    // ---- phase 2 ----
    short8 bf2[4][6];
#pragma unroll
    for (int kt = 0; kt < 4; kt++)
#pragma unroll
        for (int nt = 0; nt < 6; nt++)
            bf2[kt][nt] = *(const short8*)&Wp2[((size_t)(kt * 6 + nt)) * 512 + l * 8];

    float4v acc2[6];
#pragma unroll
    for (int nt = 0; nt < 6; nt++) acc2[nt] = (float4v)0.f;

    const int lrow = wave * 16 + lo16;   // local A row for this wave
#pragma unroll
    for (int kt = 0; kt < 4; kt++) {
        short8 af = *(const short8*)&Hs[lrow][kt * 32 + q * 8];
#pragma unroll
        for (int nt = 0; nt < 6; nt++)
            acc2[nt] = __builtin_amdgcn_mfma_f32_16x16x32_bf16(af, bf2[kt][nt], acc2[nt], 0, 0, 0);
    }

    const int row16 = m0 + wave * 16;
#pragma unroll
    for (int nt = 0; nt < 6; nt++) {
#pragma unroll
        for (int reg = 0; reg < 4; reg++) {
            int row = row16 + q * 4 + reg;
            if (row >= NN) continue;
            int col = nt * 16 + lo16;
            if (nt < 4) {
                float v = acc2[nt][reg];
                unsigned int p8 = __builtin_amdgcn_cvt_pk_fp8_f32(v, v, 0, false);
                T2q[(size_t)row * 64 + col] = (unsigned char)(p8 & 0xffu);
            } else {
                T2r[(size_t)row * 32 + (col - 64)] = acc2[nt][reg] + b2[col - 64];
            }
        }
    }
}

// ===========================================================================
// Layer-2 aggregation + finalize, REWORKED: 4 lanes x 16B per edge = full
// 64B T2q row -> 16 edges per wave-load (was 4). Grid-stride waves.
// Lane = o16*4 + h4; h4<2 reads (1-u)-cols 0..31, h4>=2 reads u-cols 32..63.
// Reduce across o16 (xor 32,16,8,4) then combine u-parts (xor 2);
// lanes 0,1 hold z[0..15]/z[16..31] and do the 32-class log_softmax.
// ===========================================================================
__global__ __launch_bounds__(256) void agg2_final(
    const int* __restrict__ rowptr, const unsigned int* __restrict__ spack,
    const unsigned char* __restrict__ T2q,
    const float* __restrict__ T2r, float* __restrict__ out)
{
    int wid = (blockIdx.x * 256 + threadIdx.x) >> 6;
    int lane = threadIdx.x & 63;
    int o16 = lane >> 2;          // edge slot 0..15
    int h4 = lane & 3;            // 16-col group
    int c16 = h4 * 16;            // byte offset into 64B fp8 row

    for (int node = wid; node < NN; node += AGG_WAVES) {
        int e0 = rowptr[node], e1 = rowptr[node + 1];

        float a[16];
#pragma unroll
        for (int d = 0; d < 16; d++) a[d] = 0.f;

        unsigned int sp0 = 0, sp1 = 0, sp2 = 0;
        uint4 g0 = make_uint4(0, 0, 0, 0), g1 = make_uint4(0, 0, 0, 0);
        if (e0 < e1) {
            int i0 = e0 + o16;      if (i0 >= e1) i0 = e1 - 1;
            int i1 = e0 + 16 + o16; if (i1 >= e1) i1 = e1 - 1;
            int i2 = e0 + 32 + o16; if (i2 >= e1) i2 = e1 - 1;
            sp0 = spack[i0];
            sp1 = spack[i1];
            sp2 = spack[i2];
            g0 = *(const uint4*)&T2q[(size_t)(sp0 >> 16) * 64 + c16];
            g1 = *(const uint4*)&T2q[(size_t)(sp1 >> 16) * 64 + c16];
        }
        for (int e = e0; e < e1; e += 16) {
            float scale = (e + o16 < e1) ? 1.f : 0.f;
            int i3 = e + 48 + o16; if (i3 >= e1) i3 = e1 - 1;
            unsigned int sp3 = spack[i3];
            uint4 g2 = *(const uint4*)&T2q[(size_t)(sp2 >> 16) * 64 + c16];
            float uu = (float)(sp0 & 0xffffu) * (1.0f / 65535.0f);
            float w = ((h4 < 2) ? (1.0f - uu) : uu) * scale;
            floatx2 fa = __builtin_amdgcn_cvt_pk_f32_fp8(g0.x, false);
            floatx2 fb = __builtin_amdgcn_cvt_pk_f32_fp8(g0.x, true);
            floatx2 fc = __builtin_amdgcn_cvt_pk_f32_fp8(g0.y, false);
            floatx2 fd = __builtin_amdgcn_cvt_pk_f32_fp8(g0.y, true);
            floatx2 fe = __builtin_amdgcn_cvt_pk_f32_fp8(g0.z, false);
            floatx2 ff = __builtin_amdgcn_cvt_pk_f32_fp8(g0.z, true);
            floatx2 fg = __builtin_amdgcn_cvt_pk_f32_fp8(g0.w, false);
            floatx2 fh = __builtin_amdgcn_cvt_pk_f32_fp8(g0.w, true);
            float xv[16] = {fa[0], fa[1], fb[0], fb[1], fc[0], fc[1], fd[0], fd[1],
                            fe[0], fe[1], ff[0], ff[1], fg[0], fg[1], fh[0], fh[1]};
#pragma unroll
            for (int d = 0; d < 16; d++) a[d] += w * xv[d];
            sp0 = sp1; sp1 = sp2; sp2 = sp3;
            g0 = g1; g1 = g2;
        }

#pragma unroll
        for (int j = 0; j < 16; j++) {
            a[j] += __shfl_xor(a[j], 32);
            a[j] += __shfl_xor(a[j], 16);
            a[j] += __shfl_xor(a[j], 8);
            a[j] += __shfl_xor(a[j], 4);
            a[j] += __shfl_xor(a[j], 2);   // (1-u)-part + u-part
        }

        // lanes 0,1: z for classes h4*16..+15
        float inv = 1.0f / fmaxf((float)(e1 - e0), 1.0f);
        float z[16];
        float4 rt0 = *(const float4*)&T2r[(size_t)node * 32 + c16 + 0];
        float4 rt1 = *(const float4*)&T2r[(size_t)node * 32 + c16 + 4];
        float4 rt2 = *(const float4*)&T2r[(size_t)node * 32 + c16 + 8];
        float4 rt3 = *(const float4*)&T2r[(size_t)node * 32 + c16 + 12];
        float rt[16] = {rt0.x, rt0.y, rt0.z, rt0.w, rt1.x, rt1.y, rt1.z, rt1.w,
                        rt2.x, rt2.y, rt2.z, rt2.w, rt3.x, rt3.y, rt3.z, rt3.w};
        float m = -3.4e38f;
#pragma unroll
        for (int j = 0; j < 16; j++) {
            z[j] = fmaxf(a[j] * inv + rt[j], 0.f);
            m = fmaxf(m, z[j]);
        }
        m = fmaxf(m, __shfl_xor(m, 1));   // combine lanes 0<->1
        float ssum = 0.f;
#pragma unroll
        for (int j = 0; j < 16; j++) ssum += __expf(z[j] - m);
        ssum += __shfl_xor(ssum, 1);
        float lg = __logf(ssum);

        if (lane < 2) {
            float4 w0, w1, w2, w3;
            w0 = make_float4(z[0] - m - lg, z[1] - m - lg, z[2] - m - lg, z[3] - m - lg);
            w1 = make_float4(z[4] - m - lg, z[5] - m - lg, z[6] - m - lg, z[7] - m - lg);
            w2 = make_float4(z[8] - m - lg, z[9] - m - lg, z[10] - m - lg, z[11] - m - lg);
            w3 = make_float4(z[12] - m - lg, z[13] - m - lg, z[14] - m - lg, z[15] - m - lg);
            *(float4*)&out[(size_t)node * 32 + c16 + 0] = w0;
            *(float4*)&out[(size_t)node * 32 + c16 + 4] = w1;
            *(float4*)&out[(size_t)node * 32 + c16 + 8] = w2;
            *(float4*)&out[(size_t)node * 32 + c16 + 12] = w3;
        }
    }
}

// ===========================================================================
extern "C" void kernel_launch(void* const* d_in, const int* in_sizes, int n_in,
                              void* d_out, int out_size, void* d_ws, size_t ws_size,
                              hipStream_t stream)
{
    const float* x  = (const float*)d_in[0];
    const int* ei   = (const int*)d_in[1];   // (2, NE)
    const float* ea = (const float*)d_in[2]; // (NE, 1)
    const float* W1 = (const float*)d_in[3]; // (2,128,128) -> flat 256x128
    const float* r1 = (const float*)d_in[4]; // (128,128)
    const float* b1 = (const float*)d_in[5]; // (128)
    const float* W2 = (const float*)d_in[6]; // (2,128,32)
    const float* r2 = (const float*)d_in[7]; // (128,32)
    const float* b2 = (const float*)d_in[8]; // (32)
    float* out = (float*)d_out;

    char* ws = (char*)d_ws;
    unsigned short* Xb  = (unsigned short*)(ws + 25600000);   // 12.8 MB
    unsigned char*  Xq  = (unsigned char*) (ws + 38400000);   // 6.4 MB (fp8 x)
    unsigned char*  T2q = (unsigned char*) (ws + 44800000);   // 3.2 MB (fp8 T2e)
    float* T2r    = (float*)(ws + 48000000);                  // 6.4 MB
    int*   rowptr = (int*)  (ws + 54400000);                  // 50001 ints
    uint2* epack8 = (uint2*)(ws + 54600064);                  // 9.63 MB
    unsigned int* spack = (unsigned int*)(ws + 64233856);     // 3.2 MB
    int* bin_counter = (int*)(ws + 67433856);                 // NBUCK ints
    unsigned short* Wp  = (unsigned short*)(ws + 67434880);   // 384*128 bf16
    unsigned short* Wp2 = (unsigned short*)(ws + 67533184);   // 128*96 bf16

    const int* esrc = ei;
    const int* edst = ei + NE;

    // --- zero bin counters (graph-capturable memset node) ---
    hipMemsetAsync(bin_counter, 0, NBUCK * sizeof(int), stream);

    // --- Fused preprocessing: pass1 (LDS-sorted coalesced) + convx + wpacks ---
    k_prep<<<PREP_TOT, 256, 0, stream>>>(x, Xb, Xq, W1, r1, Wp, W2, r2, Wp2,
                                         esrc, edst, ea, bin_counter, epack8);

    // --- CSR pass 2 (counting sort, 1024 threads/block) ---
    k_pass2<<<NBUCK, 1024, 0, stream>>>(epack8, bin_counter, spack, rowptr);

    // --- FUSED layer-1 aggregation + GEMM1 + GEMM2 (wide-load gather) ---
    gemm12_fused<<<(NN + 63) / 64, 256, 0, stream>>>(rowptr, spack, Xq, Xb,
                                                     Wp, b1, Wp2, b2, T2q, T2r);

    // --- Layer 2 aggregation + finalize (wide-load gather, grid-stride) ---
    agg2_final<<<AGG_BLOCKS, 256, 0, stream>>>(rowptr, spack, T2q, T2r, out);
}

// Round 12
// 242.020 us; speedup vs baseline: 1.0658x; 1.0658x over previous
//
#include <hip/hip_runtime.h>
#include <hip/hip_bf16.h>

constexpr int NN = 50000;   // nodes
constexpr int NE = 800000;  // edges
constexpr int NBUCK = (NN + 255) / 256;   // 196 buckets of 256 nodes
constexpr int P1B = (NE + 4095) / 4096;   // 196 pass-1 blocks
constexpr int BCAP = 6144;                // bucket capacity (mean 4082, sigma 64)

// k_prep blockIdx ranges: [pass1 | convx(grid-stride) | wpack1 | wpack2]
constexpr int PREP_CONVX_B = 1563;                   // grid-stride: 4 items/thread
constexpr int PREP_WP1 = (384 * 128 + 255) / 256;    // 192
constexpr int PREP_WP2 = (128 * 96 + 255) / 256;     // 48
constexpr int PREP_TOT = P1B + PREP_CONVX_B + PREP_WP1 + PREP_WP2;

constexpr int AGG_BLOCKS = 2048;          // 8192 waves grid-stride
constexpr int AGG_WAVES = AGG_BLOCKS * 4;

typedef __attribute__((ext_vector_type(8))) short short8;
typedef __attribute__((ext_vector_type(4))) float float4v;
typedef __attribute__((ext_vector_type(2))) float floatx2;
typedef __attribute__((ext_vector_type(4))) unsigned int uint4v;   // NT-store-safe

__device__ __forceinline__ unsigned short f2bf(float f) {
    unsigned int u = __builtin_bit_cast(unsigned int, f);
    u += 0x7FFFu + ((u >> 16) & 1u);   // round-to-nearest-even
    return (unsigned short)(u >> 16);
}
__device__ __forceinline__ unsigned int pack2bf(float lo, float hi) {
    return (unsigned int)f2bf(lo) | ((unsigned int)f2bf(hi) << 16);
}

// ===========================================================================
// Fused preprocessing (R6-verified): CSR pass1 (block-local counting sort ->
// coalesced bucket writes) | convx (bf16 + TWO fp8 half-feature planes) |
// wpack1 | wpack2.  bin_counter zeroed by memset node before this kernel.
// Xq split into 3.2MB planes so each agg1 pass's gather table fits the 4MB
// per-XCD L2 (R8-R10 PMC: gather invariant to occupancy/depth/width =>
// L2-miss (MSHR x L3-latency) throughput-bound; plane residency cuts miss
// latency ~900cy -> ~200cy).
// ===========================================================================
__global__ __launch_bounds__(256) void k_prep(
    const float* __restrict__ x, unsigned short* __restrict__ Xb,
    unsigned char* __restrict__ Xq_lo, unsigned char* __restrict__ Xq_hi,
    const float* __restrict__ W1flat, const float* __restrict__ root1,
    unsigned short* __restrict__ Wp,
    const float* __restrict__ W2, const float* __restrict__ root2,
    unsigned short* __restrict__ Wp2,
    const int* __restrict__ esrc, const int* __restrict__ edst,
    const float* __restrict__ u,
    int* __restrict__ bin_counter, uint2* __restrict__ epack8)
{
    int b = blockIdx.x, t = threadIdx.x;
    if (b < P1B) {
        __shared__ int cnt[256];     // per-bin block-local histogram
        __shared__ int base[256];    // global reservation base (slot in bucket)
        __shared__ int off[256];     // inclusive scan of cnt
        __shared__ int pos[256];     // per-bin running counter
        __shared__ uint2 se[4096];   // staged edges, sorted by bin (32 KB)
        __shared__ int sa[4096];     // global destination slot (16 KB)
        int e0 = b * 4096;
        int e1 = min(e0 + 4096, NE);
        cnt[t] = 0;
        pos[t] = 0;
        __syncthreads();
        for (int e = e0 + t; e < e1; e += 256)
            atomicAdd(&cnt[edst[e] >> 8], 1);
        __syncthreads();
        base[t] = (t < NBUCK && cnt[t] > 0) ? atomicAdd(&bin_counter[t], cnt[t]) : 0;
        off[t] = cnt[t];
        __syncthreads();
#pragma unroll
        for (int o = 1; o < 256; o <<= 1) {
            int add = (t >= o) ? off[t - o] : 0;
            __syncthreads();
            off[t] += add;
            __syncthreads();
        }
        for (int e = e0 + t; e < e1; e += 256) {
            int d = edst[e];
            int bin = d >> 8;
            int k = atomicAdd(&pos[bin], 1);
            int ls = off[bin] - cnt[bin] + k;   // block-local sorted slot
            int gs = base[bin] + k;             // slot within global bucket
            float uf = u[e] * 65535.0f + 0.5f;
            unsigned int u16 = (unsigned int)uf;
            if (u16 > 65535u) u16 = 65535u;
            uint2 v;
            v.x = ((unsigned int)esrc[e] << 16) | u16;
            v.y = (unsigned int)(d & 255);
            se[ls] = v;
            sa[ls] = (gs < BCAP) ? (bin * BCAP + gs) : -1;
        }
        __syncthreads();
        int ecnt = e1 - e0;
        for (int i = t; i < ecnt; i += 256) {
            int a = sa[i];
            if (a >= 0) epack8[a] = se[i];
        }
    } else if (b < P1B + PREP_CONVX_B) {
        int bb = b - P1B;
        for (int gid = bb * 256 + t; gid < NN * 32; gid += PREP_CONVX_B * 256) {
            int node = gid >> 5;
            int c = (gid & 31) * 4;
            float4 v = *(const float4*)&x[(size_t)node * 128 + c];
            uint2 o;
            o.x = pack2bf(v.x, v.y);
            o.y = pack2bf(v.z, v.w);
            *(uint2*)&Xb[(size_t)node * 128 + c] = o;
            unsigned int q8 = __builtin_amdgcn_cvt_pk_fp8_f32(v.x, v.y, 0, false);
            q8 = __builtin_amdgcn_cvt_pk_fp8_f32(v.z, v.w, q8, true);
            unsigned char* plane = (c < 64) ? Xq_lo : Xq_hi;
            *(unsigned int*)&plane[(size_t)node * 64 + (c & 63)] = q8;
        }
    } else if (b < P1B + PREP_CONVX_B + PREP_WP1) {
        int o = (b - P1B - PREP_CONVX_B) * 256 + t;
        if (o < 384 * 128) {
            int j = o & 7, l = (o >> 3) & 63, fi = o >> 9;
            int nt = fi & 7, kt = fi >> 3;
            int k = kt * 32 + (l >> 4) * 8 + j;
            int n = nt * 16 + (l & 15);
            float v = (k < 256) ? W1flat[k * 128 + n] : root1[(k - 256) * 128 + n];
            Wp[o] = f2bf(v);
        }
    } else {
        int o = (b - P1B - PREP_CONVX_B - PREP_WP1) * 256 + t;
        if (o < 128 * 96) {
            int j = o & 7, l = (o >> 3) & 63, fi = o >> 9;
            int nt = fi % 6, kt = fi / 6;
            int k = kt * 32 + (l >> 4) * 8 + j;
            int c = nt * 16 + (l & 15);
            float v = (c < 64) ? W2[(c >> 5) * 4096 + k * 32 + (c & 31)]
                               : root2[k * 32 + (c - 64)];
            Wp2[o] = f2bf(v);
        }
    }
}

// ===========================================================================
// Pass 2 (1024 threads): inline bin-count scan (ebase) + per-bucket LDS
// counting sort -> rowptr + compact final spack (coalesced). [R6-verified]
// ===========================================================================
__global__ __launch_bounds__(1024) void k_pass2(
    const uint2* __restrict__ epack8, const int* __restrict__ bin_counter,
    unsigned int* __restrict__ spack, int* __restrict__ rowptr)
{
    __shared__ int bsum[256];
    __shared__ int pos[256];
    __shared__ unsigned int sorted[BCAP];
    int b = blockIdx.x, t = threadIdx.x;

    if (t < 256) bsum[t] = (t < NBUCK) ? bin_counter[t] : 0;
    __syncthreads();
#pragma unroll
    for (int off = 1; off < 256; off <<= 1) {
        int add = (t >= off && t < 256) ? bsum[t - off] : 0;
        __syncthreads();
        if (t < 256) bsum[t] += add;
        __syncthreads();
    }
    int myCnt = bin_counter[b];
    int ebase = bsum[b] - myCnt;
    int ecnt = min(myCnt, BCAP);

    if (t < 256) pos[t] = 0;
    __syncthreads();
    for (int i = t; i < ecnt; i += 1024) {
        uint2 e = epack8[(size_t)b * BCAP + i];
        atomicAdd(&pos[e.y], 1);
    }
    __syncthreads();
    int v = (t < 256) ? pos[t] : 0;
    __syncthreads();
#pragma unroll
    for (int off = 1; off < 256; off <<= 1) {
        int add = (t >= off && t < 256) ? pos[t - off] : 0;
        __syncthreads();
        if (t < 256) pos[t] += add;
        __syncthreads();
    }
    int excl = (t < 256) ? (pos[t] - v) : 0;
    int node = b * 256 + t;
    if (t < 256 && node < NN) rowptr[node] = ebase + excl;
    if (b == NBUCK - 1 && t == 0) rowptr[NN] = NE;
    __syncthreads();
    if (t < 256) pos[t] = excl;
    __syncthreads();
    for (int i = t; i < ecnt; i += 1024) {
        uint2 e = epack8[(size_t)b * BCAP + i];
        int slot = atomicAdd(&pos[e.y], 1);
        if (slot < BCAP) sorted[slot] = e.x;
    }
    __syncthreads();
    for (int i = t; i < ecnt; i += 1024)
        spack[ebase + i] = sorted[i];
}

// ===========================================================================
// Layer-1 aggregation over ONE 3.2MB half-feature plane (L2-resident).
// 8 lanes x 8B per edge (64B row) -> 8 edges per trip; 3-window pipeline.
// NT spack loads + NT Ag stores keep the plane resident in L2.
// PLANE=0: feature cols 0..63 -> Ag cols [0..63] and [128..191];
// PLANE=1: cols 64..127 -> Ag cols [64..127] and [192..255].
// ===========================================================================
template<int PLANE>
__global__ __launch_bounds__(256) void agg1_plane(
    const int* __restrict__ rowptr, const unsigned int* __restrict__ spack,
    const unsigned char* __restrict__ Xqp, unsigned short* __restrict__ Ag)
{
    int wid = (blockIdx.x * 256 + threadIdx.x) >> 6;
    int lane = threadIdx.x & 63;
    int o = lane >> 3;            // edge slot 0..7
    int h = lane & 7;             // 8-col group
    int c8 = h * 8;               // byte offset within 64B plane row

    for (int node = wid; node < NN; node += AGG_WAVES) {
        int e0 = rowptr[node], e1 = rowptr[node + 1];

        float sx[8] = {0.f, 0.f, 0.f, 0.f, 0.f, 0.f, 0.f, 0.f};
        float su[8] = {0.f, 0.f, 0.f, 0.f, 0.f, 0.f, 0.f, 0.f};

        unsigned int sp0 = 0, sp1 = 0, sp2 = 0;
        uint2 g0 = make_uint2(0, 0), g1 = make_uint2(0, 0);
        if (e0 < e1) {
            int i0 = e0 + o;      if (i0 >= e1) i0 = e1 - 1;
            int i1 = e0 + 8 + o;  if (i1 >= e1) i1 = e1 - 1;
            int i2 = e0 + 16 + o; if (i2 >= e1) i2 = e1 - 1;
            sp0 = __builtin_nontemporal_load(&spack[i0]);
            sp1 = __builtin_nontemporal_load(&spack[i1]);
            sp2 = __builtin_nontemporal_load(&spack[i2]);
            g0 = *(const uint2*)&Xqp[(size_t)(sp0 >> 16) * 64 + c8];
            g1 = *(const uint2*)&Xqp[(size_t)(sp1 >> 16) * 64 + c8];
        }
        for (int e = e0; e < e1; e += 8) {
            float scale = (e + o < e1) ? 1.f : 0.f;
            int i3 = e + 24 + o; if (i3 >= e1) i3 = e1 - 1;
            unsigned int sp3 = __builtin_nontemporal_load(&spack[i3]);
            uint2 g2 = *(const uint2*)&Xqp[(size_t)(sp2 >> 16) * 64 + c8];
            float uu = (float)(sp0 & 0xffffu) * (1.0f / 65535.0f);
            float us = uu * scale;
            floatx2 f01 = __builtin_amdgcn_cvt_pk_f32_fp8(g0.x, false);
            floatx2 f23 = __builtin_amdgcn_cvt_pk_f32_fp8(g0.x, true);
            floatx2 f45 = __builtin_amdgcn_cvt_pk_f32_fp8(g0.y, false);
            floatx2 f67 = __builtin_amdgcn_cvt_pk_f32_fp8(g0.y, true);
            float xv[8] = {f01[0], f01[1], f23[0], f23[1], f45[0], f45[1], f67[0], f67[1]};
#pragma unroll
            for (int d = 0; d < 8; d++) {
                sx[d] += scale * xv[d];
                su[d] += us * xv[d];
            }
            sp0 = sp1; sp1 = sp2; sp2 = sp3;
            g0 = g1; g1 = g2;
        }

#pragma unroll
        for (int j = 0; j < 8; j++) {
            sx[j] += __shfl_xor(sx[j], 32);
            su[j] += __shfl_xor(su[j], 32);
            sx[j] += __shfl_xor(sx[j], 16);
            su[j] += __shfl_xor(su[j], 16);
            sx[j] += __shfl_xor(sx[j], 8);
            su[j] += __shfl_xor(su[j], 8);
        }

        if (lane < 8) {   // o==0 lanes hold totals for cols h*8..+7 (h=lane)
            float inv = 1.0f / fmaxf((float)(e1 - e0), 1.0f);
            uint4v o0, o1;
            o0.x = pack2bf((sx[0] - su[0]) * inv, (sx[1] - su[1]) * inv);
            o0.y = pack2bf((sx[2] - su[2]) * inv, (sx[3] - su[3]) * inv);
            o0.z = pack2bf((sx[4] - su[4]) * inv, (sx[5] - su[5]) * inv);
            o0.w = pack2bf((sx[6] - su[6]) * inv, (sx[7] - su[7]) * inv);
            o1.x = pack2bf(su[0] * inv, su[1] * inv);
            o1.y = pack2bf(su[2] * inv, su[3] * inv);
            o1.z = pack2bf(su[4] * inv, su[5] * inv);
            o1.w = pack2bf(su[6] * inv, su[7] * inv);
            const int base = PLANE ? 64 : 0;
            __builtin_nontemporal_store(o0, (uint4v*)&Ag[(size_t)node * 256 + base + c8]);
            __builtin_nontemporal_store(o1, (uint4v*)&Ag[(size_t)node * 256 + 128 + base + c8]);
        }
    }
}

// ===========================================================================
// Fused GEMM1+GEMM2 via bf16 MFMA [R6-verified]. Phase 1: H = relu([Ag|Xb]
// @ Wb + b1) into LDS (bf16). Phase 2: [T2q(fp8)|T2r(fp32)] = H @ Wb2.
// ===========================================================================
__global__ __launch_bounds__(256) void gemm12_mfma(
    const unsigned short* __restrict__ Ag,
    const unsigned short* __restrict__ Xb,
    const unsigned short* __restrict__ Wp,
    const float* __restrict__ bias1,
    const unsigned short* __restrict__ Wp2,
    const float* __restrict__ b2,
    unsigned char* __restrict__ T2q, float* __restrict__ T2r)
{
    __shared__ unsigned short Hs[64][136];
    const int t = threadIdx.x;
    const int wave = t >> 6, l = t & 63;
    const int lo16 = l & 15, q = l >> 4;
    const int m0 = blockIdx.x * 64;

    // ---- phase 1 ----
    short8 bf[12][2];
#pragma unroll
    for (int kt = 0; kt < 12; kt++)
#pragma unroll
        for (int nl = 0; nl < 2; nl++)
            bf[kt][nl] = *(const short8*)&Wp[((size_t)(kt * 8 + wave * 2 + nl)) * 512 + l * 8];

    float4v acc[4][2];
#pragma unroll
    for (int mt = 0; mt < 4; mt++) {
        acc[mt][0] = (float4v)0.f;
        acc[mt][1] = (float4v)0.f;
    }

    int rows[4];
#pragma unroll
    for (int mt = 0; mt < 4; mt++) {
        int r = m0 + mt * 16 + lo16;
        rows[mt] = (r < NN) ? r : (NN - 1);  // clamp; stores predicated
    }

#pragma unroll
    for (int kt = 0; kt < 12; kt++) {
#pragma unroll
        for (int mt = 0; mt < 4; mt++) {
            short8 af;
            if (kt < 8)
                af = *(const short8*)&Ag[(size_t)rows[mt] * 256 + kt * 32 + q * 8];
            else
                af = *(const short8*)&Xb[(size_t)rows[mt] * 128 + (kt - 8) * 32 + q * 8];
            acc[mt][0] = __builtin_amdgcn_mfma_f32_16x16x32_bf16(af, bf[kt][0], acc[mt][0], 0, 0, 0);
            acc[mt][1] = __builtin_amdgcn_mfma_f32_16x16x32_bf16(af, bf[kt][1], acc[mt][1], 0, 0, 0);
        }
    }

    const int c0 = wave * 32;
    float b0 = bias1[c0 + lo16];
    float b1v = bias1[c0 + 16 + lo16];
#pragma unroll
    for (int mt = 0; mt < 4; mt++) {
#pragma unroll
        for (int reg = 0; reg < 4; reg++) {
            int lr = mt * 16 + q * 4 + reg;   // local row in tile
            Hs[lr][c0 + lo16] = f2bf(fmaxf(acc[mt][0][reg] + b0, 0.f));
            Hs[lr][c0 + 16 + lo16] = f2bf(fmaxf(acc[mt][1][reg] + b1v, 0.f));
        }
    }
    __syncthreads();

    // ---- phase 2 ----
    short8 bf2[4][6];
#pragma unroll
    for (int kt = 0; kt < 4; kt++)
#pragma unroll
        for (int nt = 0; nt < 6; nt++)
            bf2[kt][nt] = *(const short8*)&Wp2[((size_t)(kt * 6 + nt)) * 512 + l * 8];

    float4v acc2[6];
#pragma unroll
    for (int nt = 0; nt < 6; nt++) acc2[nt] = (float4v)0.f;

    const int lrow = wave * 16 + lo16;   // local A row for this wave
#pragma unroll
    for (int kt = 0; kt < 4; kt++) {
        short8 af = *(const short8*)&Hs[lrow][kt * 32 + q * 8];
#pragma unroll
        for (int nt = 0; nt < 6; nt++)
            acc2[nt] = __builtin_amdgcn_mfma_f32_16x16x32_bf16(af, bf2[kt][nt], acc2[nt], 0, 0, 0);
    }

    const int row16 = m0 + wave * 16;
#pragma unroll
    for (int nt = 0; nt < 6; nt++) {
#pragma unroll
        for (int reg = 0; reg < 4; reg++) {
            int row = row16 + q * 4 + reg;
            if (row >= NN) continue;
            int col = nt * 16 + lo16;
            if (nt < 4) {
                float v = acc2[nt][reg];
                unsigned int p8 = __builtin_amdgcn_cvt_pk_fp8_f32(v, v, 0, false);
                T2q[(size_t)row * 64 + col] = (unsigned char)(p8 & 0xffu);
            } else {
                T2r[(size_t)row * 32 + (col - 64)] = acc2[nt][reg] + b2[col - 64];
            }
        }
    }
}

// ===========================================================================
// Layer-2 aggregation + finalize [R6-verified] + NT spack loads / NT out
// stores (T2q table is 3.2MB -> already L2-resident; keep it that way).
// ===========================================================================
__global__ __launch_bounds__(256) void agg2_final(
    const int* __restrict__ rowptr, const unsigned int* __restrict__ spack,
    const unsigned char* __restrict__ T2q,
    const float* __restrict__ T2r, float* __restrict__ out)
{
    int wid = (blockIdx.x * 256 + threadIdx.x) >> 6;
    int lane = threadIdx.x & 63;
    int q = lane >> 4, hl = lane & 15;
    int c4 = hl * 4;

    for (int node = wid; node < NN; node += AGG_WAVES) {
        int e0 = rowptr[node], e1 = rowptr[node + 1];

        float a[4] = {0.f, 0.f, 0.f, 0.f};
        unsigned int sp0 = 0, sp1 = 0, sp2 = 0;
        unsigned int g0 = 0, g1 = 0;
        if (e0 < e1) {
            int i0 = e0 + q;     if (i0 >= e1) i0 = e1 - 1;
            int i1 = e0 + 4 + q; if (i1 >= e1) i1 = e1 - 1;
            int i2 = e0 + 8 + q; if (i2 >= e1) i2 = e1 - 1;
            sp0 = __builtin_nontemporal_load(&spack[i0]);
            sp1 = __builtin_nontemporal_load(&spack[i1]);
            sp2 = __builtin_nontemporal_load(&spack[i2]);
            g0 = *(const unsigned int*)&T2q[(size_t)(sp0 >> 16) * 64 + c4];
            g1 = *(const unsigned int*)&T2q[(size_t)(sp1 >> 16) * 64 + c4];
        }
        for (int e = e0; e < e1; e += 4) {
            float scale = (e + q < e1) ? 1.f : 0.f;
            int i3 = e + 12 + q; if (i3 >= e1) i3 = e1 - 1;
            unsigned int sp3 = __builtin_nontemporal_load(&spack[i3]);
            unsigned int g2 = *(const unsigned int*)&T2q[(size_t)(sp2 >> 16) * 64 + c4];
            float uu = (float)(sp0 & 0xffffu) * (1.0f / 65535.0f);
            float w = ((hl < 8) ? (1.0f - uu) : uu) * scale;
            floatx2 f01 = __builtin_amdgcn_cvt_pk_f32_fp8(g0, false);
            floatx2 f23 = __builtin_amdgcn_cvt_pk_f32_fp8(g0, true);
            a[0] += w * f01[0];
            a[1] += w * f01[1];
            a[2] += w * f23[0];
            a[3] += w * f23[1];
            sp0 = sp1; sp1 = sp2; sp2 = sp3;
            g0 = g1; g1 = g2;
        }

#pragma unroll
        for (int j = 0; j < 4; j++) {
            a[j] += __shfl_xor(a[j], 32);
            a[j] += __shfl_xor(a[j], 16);
            a[j] += __shfl_xor(a[j], 8);  // z[c] = (1-u)-part + u-part
        }

        float inv = 1.0f / fmaxf((float)(e1 - e0), 1.0f);
        int oc = (hl & 7) * 4;
        float4 rt = *(const float4*)&T2r[(size_t)node * 32 + oc];
        float z0 = fmaxf(a[0] * inv + rt.x, 0.f);
        float z1 = fmaxf(a[1] * inv + rt.y, 0.f);
        float z2 = fmaxf(a[2] * inv + rt.z, 0.f);
        float z3 = fmaxf(a[3] * inv + rt.w, 0.f);

        float m = fmaxf(fmaxf(z0, z1), fmaxf(z2, z3));
#pragma unroll
        for (int off = 4; off > 0; off >>= 1) m = fmaxf(m, __shfl_xor(m, off));
        float ssum = __expf(z0 - m) + __expf(z1 - m) + __expf(z2 - m) + __expf(z3 - m);
#pragma unroll
        for (int off = 4; off > 0; off >>= 1) ssum += __shfl_xor(ssum, off);
        float lg = __logf(ssum);

        if (lane < 8) {
            float4v o;
            o.x = z0 - m - lg;
            o.y = z1 - m - lg;
            o.z = z2 - m - lg;
            o.w = z3 - m - lg;
            __builtin_nontemporal_store(o, (float4v*)&out[(size_t)node * 32 + oc]);
        }
    }
}

// ===========================================================================
extern "C" void kernel_launch(void* const* d_in, const int* in_sizes, int n_in,
                              void* d_out, int out_size, void* d_ws, size_t ws_size,
                              hipStream_t stream)
{
    const float* x  = (const float*)d_in[0];
    const int* ei   = (const int*)d_in[1];   // (2, NE)
    const float* ea = (const float*)d_in[2]; // (NE, 1)
    const float* W1 = (const float*)d_in[3]; // (2,128,128) -> flat 256x128
    const float* r1 = (const float*)d_in[4]; // (128,128)
    const float* b1 = (const float*)d_in[5]; // (128)
    const float* W2 = (const float*)d_in[6]; // (2,128,32)
    const float* r2 = (const float*)d_in[7]; // (128,32)
    const float* b2 = (const float*)d_in[8]; // (32)
    float* out = (float*)d_out;

    char* ws = (char*)d_ws;
    unsigned short* Ag  = (unsigned short*)(ws);              // 25.6 MB
    unsigned short* Xb  = (unsigned short*)(ws + 25600000);   // 12.8 MB
    unsigned char*  Xq_lo = (unsigned char*)(ws + 38400000);  // 3.2 MB (fp8 cols 0-63)
    unsigned char*  Xq_hi = (unsigned char*)(ws + 41600000);  // 3.2 MB (fp8 cols 64-127)
    unsigned char*  T2q = (unsigned char*) (ws + 44800000);   // 3.2 MB (fp8 T2e)
    float* T2r    = (float*)(ws + 48000000);                  // 6.4 MB
    int*   rowptr = (int*)  (ws + 54400000);                  // 50001 ints
    uint2* epack8 = (uint2*)(ws + 54600064);                  // 9.63 MB
    unsigned int* spack = (unsigned int*)(ws + 64233856);     // 3.2 MB
    int* bin_counter = (int*)(ws + 67433856);                 // NBUCK ints
    unsigned short* Wp  = (unsigned short*)(ws + 67434880);   // 384*128 bf16
    unsigned short* Wp2 = (unsigned short*)(ws + 67533184);   // 128*96 bf16

    const int* esrc = ei;
    const int* edst = ei + NE;

    // --- zero bin counters (graph-capturable memset node) ---
    (void)hipMemsetAsync(bin_counter, 0, NBUCK * sizeof(int), stream);

    // --- Fused preprocessing: pass1 + convx (2 planes) + wpacks ---
    k_prep<<<PREP_TOT, 256, 0, stream>>>(x, Xb, Xq_lo, Xq_hi, W1, r1, Wp,
                                         W2, r2, Wp2, esrc, edst, ea,
                                         bin_counter, epack8);

    // --- CSR pass 2 (counting sort, 1024 threads/block) ---
    k_pass2<<<NBUCK, 1024, 0, stream>>>(epack8, bin_counter, spack, rowptr);

    // --- Layer 1 aggregation: two L2-resident half-feature passes ---
    agg1_plane<0><<<AGG_BLOCKS, 256, 0, stream>>>(rowptr, spack, Xq_lo, Ag);
    agg1_plane<1><<<AGG_BLOCKS, 256, 0, stream>>>(rowptr, spack, Xq_hi, Ag);

    // --- Fused GEMM1+GEMM2 ---
    gemm12_mfma<<<(NN + 63) / 64, 256, 0, stream>>>(Ag, Xb, Wp, b1, Wp2, b2,
                                                    T2q, T2r);

    // --- Layer 2 aggregation + finalize ---
    agg2_final<<<AGG_BLOCKS, 256, 0, stream>>>(rowptr, spack, T2q, T2r, out);
}

// Round 13
// 204.163 us; speedup vs baseline: 1.2634x; 1.1854x over previous
//
#include <hip/hip_runtime.h>
#include <hip/hip_bf16.h>

constexpr int NN = 50000;   // nodes
constexpr int NE = 800000;  // edges
constexpr int NBUCK = (NN + 255) / 256;   // 196 buckets of 256 nodes
constexpr int P1B = (NE + 4095) / 4096;   // 196 pass-1 blocks
constexpr int BCAP = 6144;                // bucket capacity (mean 4082, sigma 64)

// k_prep blockIdx ranges: [pass1 | convx(grid-stride) | wpack1 | wpack2]
constexpr int PREP_CONVX_B = 1563;                   // grid-stride: 4 items/thread
constexpr int PREP_WP1 = (384 * 128 + 255) / 256;    // 192
constexpr int PREP_WP2 = (128 * 96 + 255) / 256;     // 48
constexpr int PREP_TOT = P1B + PREP_CONVX_B + PREP_WP1 + PREP_WP2;

constexpr int AGG_BLOCKS = 2048;          // 8192 waves, ~6 nodes/wave grid-stride
constexpr int AGG_WAVES = AGG_BLOCKS * 4;

typedef __attribute__((ext_vector_type(8))) short short8;
typedef __attribute__((ext_vector_type(4))) float float4v;
typedef __attribute__((ext_vector_type(2))) float floatx2;

__device__ __forceinline__ unsigned short f2bf(float f) {
    unsigned int u = __builtin_bit_cast(unsigned int, f);
    u += 0x7FFFu + ((u >> 16) & 1u);   // round-to-nearest-even
    return (unsigned short)(u >> 16);
}
__device__ __forceinline__ unsigned int pack2bf(float lo, float hi) {
    return (unsigned int)f2bf(lo) | ((unsigned int)f2bf(hi) << 16);
}

// ===========================================================================
// Fused preprocessing (R6-verified): CSR pass1 (block-local counting sort ->
// coalesced bucket writes) | convx (bf16+fp8, grid-stride) | wpack1 | wpack2.
// bin_counter zeroed by memset node before this kernel.
// ===========================================================================
__global__ __launch_bounds__(256) void k_prep(
    const float* __restrict__ x, unsigned short* __restrict__ Xb,
    unsigned char* __restrict__ Xq,
    const float* __restrict__ W1flat, const float* __restrict__ root1,
    unsigned short* __restrict__ Wp,
    const float* __restrict__ W2, const float* __restrict__ root2,
    unsigned short* __restrict__ Wp2,
    const int* __restrict__ esrc, const int* __restrict__ edst,
    const float* __restrict__ u,
    int* __restrict__ bin_counter, uint2* __restrict__ epack8)
{
    int b = blockIdx.x, t = threadIdx.x;
    if (b < P1B) {
        __shared__ int cnt[256];     // per-bin block-local histogram
        __shared__ int base[256];    // global reservation base (slot in bucket)
        __shared__ int off[256];     // inclusive scan of cnt
        __shared__ int pos[256];     // per-bin running counter
        __shared__ uint2 se[4096];   // staged edges, sorted by bin (32 KB)
        __shared__ int sa[4096];     // global destination slot (16 KB)
        int e0 = b * 4096;
        int e1 = min(e0 + 4096, NE);
        cnt[t] = 0;
        pos[t] = 0;
        __syncthreads();
        for (int e = e0 + t; e < e1; e += 256)
            atomicAdd(&cnt[edst[e] >> 8], 1);
        __syncthreads();
        base[t] = (t < NBUCK && cnt[t] > 0) ? atomicAdd(&bin_counter[t], cnt[t]) : 0;
        off[t] = cnt[t];
        __syncthreads();
#pragma unroll
        for (int o = 1; o < 256; o <<= 1) {
            int add = (t >= o) ? off[t - o] : 0;
            __syncthreads();
            off[t] += add;
            __syncthreads();
        }
        for (int e = e0 + t; e < e1; e += 256) {
            int d = edst[e];
            int bin = d >> 8;
            int k = atomicAdd(&pos[bin], 1);
            int ls = off[bin] - cnt[bin] + k;   // block-local sorted slot
            int gs = base[bin] + k;             // slot within global bucket
            float uf = u[e] * 65535.0f + 0.5f;
            unsigned int u16 = (unsigned int)uf;
            if (u16 > 65535u) u16 = 65535u;
            uint2 v;
            v.x = ((unsigned int)esrc[e] << 16) | u16;
            v.y = (unsigned int)(d & 255);
            se[ls] = v;
            sa[ls] = (gs < BCAP) ? (bin * BCAP + gs) : -1;
        }
        __syncthreads();
        int ecnt = e1 - e0;
        for (int i = t; i < ecnt; i += 256) {
            int a = sa[i];
            if (a >= 0) epack8[a] = se[i];
        }
    } else if (b < P1B + PREP_CONVX_B) {
        int bb = b - P1B;
        for (int gid = bb * 256 + t; gid < NN * 32; gid += PREP_CONVX_B * 256) {
            int node = gid >> 5;
            int c = (gid & 31) * 4;
            float4 v = *(const float4*)&x[(size_t)node * 128 + c];
            uint2 o;
            o.x = pack2bf(v.x, v.y);
            o.y = pack2bf(v.z, v.w);
            *(uint2*)&Xb[(size_t)node * 128 + c] = o;
            unsigned int q8 = __builtin_amdgcn_cvt_pk_fp8_f32(v.x, v.y, 0, false);
            q8 = __builtin_amdgcn_cvt_pk_fp8_f32(v.z, v.w, q8, true);
            *(unsigned int*)&Xq[(size_t)node * 128 + c] = q8;
        }
    } else if (b < P1B + PREP_CONVX_B + PREP_WP1) {
        int o = (b - P1B - PREP_CONVX_B) * 256 + t;
        if (o < 384 * 128) {
            int j = o & 7, l = (o >> 3) & 63, fi = o >> 9;
            int nt = fi & 7, kt = fi >> 3;
            int k = kt * 32 + (l >> 4) * 8 + j;
            int n = nt * 16 + (l & 15);
            float v = (k < 256) ? W1flat[k * 128 + n] : root1[(k - 256) * 128 + n];
            Wp[o] = f2bf(v);
        }
    } else {
        int o = (b - P1B - PREP_CONVX_B - PREP_WP1) * 256 + t;
        if (o < 128 * 96) {
            int j = o & 7, l = (o >> 3) & 63, fi = o >> 9;
            int nt = fi % 6, kt = fi / 6;
            int k = kt * 32 + (l >> 4) * 8 + j;
            int c = nt * 16 + (l & 15);
            float v = (c < 64) ? W2[(c >> 5) * 4096 + k * 32 + (c & 31)]
                               : root2[k * 32 + (c - 64)];
            Wp2[o] = f2bf(v);
        }
    }
}

// ===========================================================================
// Pass 2 (1024 threads): inline bin-count scan (ebase) + per-bucket LDS
// counting sort -> rowptr + compact final spack (coalesced). [R6-verified]
// ===========================================================================
__global__ __launch_bounds__(1024) void k_pass2(
    const uint2* __restrict__ epack8, const int* __restrict__ bin_counter,
    unsigned int* __restrict__ spack, int* __restrict__ rowptr)
{
    __shared__ int bsum[256];
    __shared__ int pos[256];
    __shared__ unsigned int sorted[BCAP];
    int b = blockIdx.x, t = threadIdx.x;

    if (t < 256) bsum[t] = (t < NBUCK) ? bin_counter[t] : 0;
    __syncthreads();
#pragma unroll
    for (int off = 1; off < 256; off <<= 1) {
        int add = (t >= off && t < 256) ? bsum[t - off] : 0;
        __syncthreads();
        if (t < 256) bsum[t] += add;
        __syncthreads();
    }
    int myCnt = bin_counter[b];
    int ebase = bsum[b] - myCnt;
    int ecnt = min(myCnt, BCAP);

    if (t < 256) pos[t] = 0;
    __syncthreads();
    for (int i = t; i < ecnt; i += 1024) {
        uint2 e = epack8[(size_t)b * BCAP + i];
        atomicAdd(&pos[e.y], 1);
    }
    __syncthreads();
    int v = (t < 256) ? pos[t] : 0;
    __syncthreads();
#pragma unroll
    for (int off = 1; off < 256; off <<= 1) {
        int add = (t >= off && t < 256) ? pos[t - off] : 0;
        __syncthreads();
        if (t < 256) pos[t] += add;
        __syncthreads();
    }
    int excl = (t < 256) ? (pos[t] - v) : 0;
    int node = b * 256 + t;
    if (t < 256 && node < NN) rowptr[node] = ebase + excl;
    if (b == NBUCK - 1 && t == 0) rowptr[NN] = NE;
    __syncthreads();
    if (t < 256) pos[t] = excl;
    __syncthreads();
    for (int i = t; i < ecnt; i += 1024) {
        uint2 e = epack8[(size_t)b * BCAP + i];
        int slot = atomicAdd(&pos[e.y], 1);
        if (slot < BCAP) sorted[slot] = e.x;
    }
    __syncthreads();
    for (int i = t; i < ecnt; i += 1024)
        spack[ebase + i] = sorted[i];
}

// ===========================================================================
// Layer-1 aggregation: GRID-STRIDE persistent waves (8192 waves, ~6 nodes
// each). Inner loop per node: 4 edges/trip, 3-window pipeline. [R6-verified]
// ===========================================================================
__global__ __launch_bounds__(256) void agg1(
    const int* __restrict__ rowptr, const unsigned int* __restrict__ spack,
    const unsigned char* __restrict__ Xq, unsigned short* __restrict__ Ag)
{
    int wid = (blockIdx.x * 256 + threadIdx.x) >> 6;
    int lane = threadIdx.x & 63;
    int q = lane >> 4, hl = lane & 15;
    int c8 = hl * 8;

    for (int node = wid; node < NN; node += AGG_WAVES) {
        int e0 = rowptr[node], e1 = rowptr[node + 1];

        float sx[8] = {0.f, 0.f, 0.f, 0.f, 0.f, 0.f, 0.f, 0.f};
        float su[8] = {0.f, 0.f, 0.f, 0.f, 0.f, 0.f, 0.f, 0.f};

        unsigned int sp0 = 0, sp1 = 0, sp2 = 0;
        uint2 g0 = make_uint2(0, 0), g1 = make_uint2(0, 0);
        if (e0 < e1) {
            int i0 = e0 + q;     if (i0 >= e1) i0 = e1 - 1;
            int i1 = e0 + 4 + q; if (i1 >= e1) i1 = e1 - 1;
            int i2 = e0 + 8 + q; if (i2 >= e1) i2 = e1 - 1;
            sp0 = spack[i0];
            sp1 = spack[i1];
            sp2 = spack[i2];
            g0 = *(const uint2*)&Xq[(size_t)(sp0 >> 16) * 128 + c8];
            g1 = *(const uint2*)&Xq[(size_t)(sp1 >> 16) * 128 + c8];
        }
        for (int e = e0; e < e1; e += 4) {
            float scale = (e + q < e1) ? 1.f : 0.f;
            int i3 = e + 12 + q; if (i3 >= e1) i3 = e1 - 1;
            unsigned int sp3 = spack[i3];
            uint2 g2 = *(const uint2*)&Xq[(size_t)(sp2 >> 16) * 128 + c8];
            float uu = (float)(sp0 & 0xffffu) * (1.0f / 65535.0f);
            float us = uu * scale;
            floatx2 f01 = __builtin_amdgcn_cvt_pk_f32_fp8(g0.x, false);
            floatx2 f23 = __builtin_amdgcn_cvt_pk_f32_fp8(g0.x, true);
            floatx2 f45 = __builtin_amdgcn_cvt_pk_f32_fp8(g0.y, false);
            floatx2 f67 = __builtin_amdgcn_cvt_pk_f32_fp8(g0.y, true);
            float xv[8] = {f01[0], f01[1], f23[0], f23[1], f45[0], f45[1], f67[0], f67[1]};
#pragma unroll
            for (int d = 0; d < 8; d++) {
                sx[d] += scale * xv[d];
                su[d] += us * xv[d];
            }
            sp0 = sp1; sp1 = sp2; sp2 = sp3;
            g0 = g1; g1 = g2;
        }

#pragma unroll
        for (int j = 0; j < 8; j++) {
            sx[j] += __shfl_xor(sx[j], 32);
            su[j] += __shfl_xor(su[j], 32);
            sx[j] += __shfl_xor(sx[j], 16);
            su[j] += __shfl_xor(su[j], 16);
        }

        if (lane < 16) {
            float inv = 1.0f / fmaxf((float)(e1 - e0), 1.0f);
            uint4 o0, o1;
            o0.x = pack2bf((sx[0] - su[0]) * inv, (sx[1] - su[1]) * inv);
            o0.y = pack2bf((sx[2] - su[2]) * inv, (sx[3] - su[3]) * inv);
            o0.z = pack2bf((sx[4] - su[4]) * inv, (sx[5] - su[5]) * inv);
            o0.w = pack2bf((sx[6] - su[6]) * inv, (sx[7] - su[7]) * inv);
            o1.x = pack2bf(su[0] * inv, su[1] * inv);
            o1.y = pack2bf(su[2] * inv, su[3] * inv);
            o1.z = pack2bf(su[4] * inv, su[5] * inv);
            o1.w = pack2bf(su[6] * inv, su[7] * inv);
            *(uint4*)&Ag[(size_t)node * 256 + c8] = o0;
            *(uint4*)&Ag[(size_t)node * 256 + 128 + c8] = o1;
        }
    }
}

// ===========================================================================
// Fused GEMM1+GEMM2 via bf16 MFMA. Phase 1: H = relu([Ag|Xb] @ Wb + b1)
// into LDS (bf16). Phase 2: [T2q(fp8) | T2r(fp32)] = H @ Wb2 (+b2 on root).
// ===========================================================================
__global__ __launch_bounds__(256) void gemm12_mfma(
    const unsigned short* __restrict__ Ag,
    const unsigned short* __restrict__ Xb,
    const unsigned short* __restrict__ Wp,
    const float* __restrict__ bias1,
    const unsigned short* __restrict__ Wp2,
    const float* __restrict__ b2,
    unsigned char* __restrict__ T2q, float* __restrict__ T2r)
{
    __shared__ unsigned short Hs[64][136];
    const int t = threadIdx.x;
    const int wave = t >> 6, l = t & 63;
    const int lo16 = l & 15, q = l >> 4;
    const int m0 = blockIdx.x * 64;

    // ---- phase 1 ----
    short8 bf[12][2];
#pragma unroll
    for (int kt = 0; kt < 12; kt++)
#pragma unroll
        for (int nl = 0; nl < 2; nl++)
            bf[kt][nl] = *(const short8*)&Wp[((size_t)(kt * 8 + wave * 2 + nl)) * 512 + l * 8];

    float4v acc[4][2];
#pragma unroll
    for (int mt = 0; mt < 4; mt++) {
        acc[mt][0] = (float4v)0.f;
        acc[mt][1] = (float4v)0.f;
    }

    int rows[4];
#pragma unroll
    for (int mt = 0; mt < 4; mt++) {
        int r = m0 + mt * 16 + lo16;
        rows[mt] = (r < NN) ? r : (NN - 1);  // clamp; stores predicated
    }

#pragma unroll
    for (int kt = 0; kt < 12; kt++) {
#pragma unroll
        for (int mt = 0; mt < 4; mt++) {
            short8 af;
            if (kt < 8)
                af = *(const short8*)&Ag[(size_t)rows[mt] * 256 + kt * 32 + q * 8];
            else
                af = *(const short8*)&Xb[(size_t)rows[mt] * 128 + (kt - 8) * 32 + q * 8];
            acc[mt][0] = __builtin_amdgcn_mfma_f32_16x16x32_bf16(af, bf[kt][0], acc[mt][0], 0, 0, 0);
            acc[mt][1] = __builtin_amdgcn_mfma_f32_16x16x32_bf16(af, bf[kt][1], acc[mt][1], 0, 0, 0);
        }
    }

    const int c0 = wave * 32;
    float b0 = bias1[c0 + lo16];
    float b1v = bias1[c0 + 16 + lo16];
#pragma unroll
    for (int mt = 0; mt < 4; mt++) {
#pragma unroll
        for (int reg = 0; reg < 4; reg++) {
            int lr = mt * 16 + q * 4 + reg;   // local row in tile
            Hs[lr][c0 + lo16] = f2bf(fmaxf(acc[mt][0][reg] + b0, 0.f));
            Hs[lr][c0 + 16 + lo16] = f2bf(fmaxf(acc[mt][1][reg] + b1v, 0.f));
        }
    }
    __syncthreads();

    // ---- phase 2 ----
    short8 bf2[4][6];
#pragma unroll
    for (int kt = 0; kt < 4; kt++)
#pragma unroll
        for (int nt = 0; nt < 6; nt++)
            bf2[kt][nt] = *(const short8*)&Wp2[((size_t)(kt * 6 + nt)) * 512 + l * 8];

    float4v acc2[6];
#pragma unroll
    for (int nt = 0; nt < 6; nt++) acc2[nt] = (float4v)0.f;

    const int lrow = wave * 16 + lo16;   // local A row for this wave
#pragma unroll
    for (int kt = 0; kt < 4; kt++) {
        short8 af = *(const short8*)&Hs[lrow][kt * 32 + q * 8];
#pragma unroll
        for (int nt = 0; nt < 6; nt++)
            acc2[nt] = __builtin_amdgcn_mfma_f32_16x16x32_bf16(af, bf2[kt][nt], acc2[nt], 0, 0, 0);
    }

    const int row16 = m0 + wave * 16;
#pragma unroll
    for (int nt = 0; nt < 6; nt++) {
#pragma unroll
        for (int reg = 0; reg < 4; reg++) {
            int row = row16 + q * 4 + reg;
            if (row >= NN) continue;
            int col = nt * 16 + lo16;
            if (nt < 4) {
                float v = acc2[nt][reg];
                unsigned int p8 = __builtin_amdgcn_cvt_pk_fp8_f32(v, v, 0, false);
                T2q[(size_t)row * 64 + col] = (unsigned char)(p8 & 0xffu);
            } else {
                T2r[(size_t)row * 32 + (col - 64)] = acc2[nt][reg] + b2[col - 64];
            }
        }
    }
}

// ===========================================================================
// Layer-2 aggregation + finalize: GRID-STRIDE persistent waves [R6-verified].
// ===========================================================================
__global__ __launch_bounds__(256) void agg2_final(
    const int* __restrict__ rowptr, const unsigned int* __restrict__ spack,
    const unsigned char* __restrict__ T2q,
    const float* __restrict__ T2r, float* __restrict__ out)
{
    int wid = (blockIdx.x * 256 + threadIdx.x) >> 6;
    int lane = threadIdx.x & 63;
    int q = lane >> 4, hl = lane & 15;
    int c4 = hl * 4;

    for (int node = wid; node < NN; node += AGG_WAVES) {
        int e0 = rowptr[node], e1 = rowptr[node + 1];

        float a[4] = {0.f, 0.f, 0.f, 0.f};
        unsigned int sp0 = 0, sp1 = 0, sp2 = 0;
        unsigned int g0 = 0, g1 = 0;
        if (e0 < e1) {
            int i0 = e0 + q;     if (i0 >= e1) i0 = e1 - 1;
            int i1 = e0 + 4 + q; if (i1 >= e1) i1 = e1 - 1;
            int i2 = e0 + 8 + q; if (i2 >= e1) i2 = e1 - 1;
            sp0 = spack[i0];
            sp1 = spack[i1];
            sp2 = spack[i2];
            g0 = *(const unsigned int*)&T2q[(size_t)(sp0 >> 16) * 64 + c4];
            g1 = *(const unsigned int*)&T2q[(size_t)(sp1 >> 16) * 64 + c4];
        }
        for (int e = e0; e < e1; e += 4) {
            float scale = (e + q < e1) ? 1.f : 0.f;
            int i3 = e + 12 + q; if (i3 >= e1) i3 = e1 - 1;
            unsigned int sp3 = spack[i3];
            unsigned int g2 = *(const unsigned int*)&T2q[(size_t)(sp2 >> 16) * 64 + c4];
            float uu = (float)(sp0 & 0xffffu) * (1.0f / 65535.0f);
            float w = ((hl < 8) ? (1.0f - uu) : uu) * scale;
            floatx2 f01 = __builtin_amdgcn_cvt_pk_f32_fp8(g0, false);
            floatx2 f23 = __builtin_amdgcn_cvt_pk_f32_fp8(g0, true);
            a[0] += w * f01[0];
            a[1] += w * f01[1];
            a[2] += w * f23[0];
            a[3] += w * f23[1];
            sp0 = sp1; sp1 = sp2; sp2 = sp3;
            g0 = g1; g1 = g2;
        }

#pragma unroll
        for (int j = 0; j < 4; j++) {
            a[j] += __shfl_xor(a[j], 32);
            a[j] += __shfl_xor(a[j], 16);
            a[j] += __shfl_xor(a[j], 8);  // z[c] = (1-u)-part + u-part
        }

        float inv = 1.0f / fmaxf((float)(e1 - e0), 1.0f);
        int oc = (hl & 7) * 4;
        float4 rt = *(const float4*)&T2r[(size_t)node * 32 + oc];
        float z0 = fmaxf(a[0] * inv + rt.x, 0.f);
        float z1 = fmaxf(a[1] * inv + rt.y, 0.f);
        float z2 = fmaxf(a[2] * inv + rt.z, 0.f);
        float z3 = fmaxf(a[3] * inv + rt.w, 0.f);

        float m = fmaxf(fmaxf(z0, z1), fmaxf(z2, z3));
#pragma unroll
        for (int off = 4; off > 0; off >>= 1) m = fmaxf(m, __shfl_xor(m, off));
        float ssum = __expf(z0 - m) + __expf(z1 - m) + __expf(z2 - m) + __expf(z3 - m);
#pragma unroll
        for (int off = 4; off > 0; off >>= 1) ssum += __shfl_xor(ssum, off);
        float lg = __logf(ssum);

        if (lane < 8) {
            float4 o = make_float4(z0 - m - lg, z1 - m - lg, z2 - m - lg, z3 - m - lg);
            *(float4*)&out[(size_t)node * 32 + oc] = o;
        }
    }
}

// ===========================================================================
extern "C" void kernel_launch(void* const* d_in, const int* in_sizes, int n_in,
                              void* d_out, int out_size, void* d_ws, size_t ws_size,
                              hipStream_t stream)
{
    const float* x  = (const float*)d_in[0];
    const int* ei   = (const int*)d_in[1];   // (2, NE)
    const float* ea = (const float*)d_in[2]; // (NE, 1)
    const float* W1 = (const float*)d_in[3]; // (2,128,128) -> flat 256x128
    const float* r1 = (const float*)d_in[4]; // (128,128)
    const float* b1 = (const float*)d_in[5]; // (128)
    const float* W2 = (const float*)d_in[6]; // (2,128,32)
    const float* r2 = (const float*)d_in[7]; // (128,32)
    const float* b2 = (const float*)d_in[8]; // (32)
    float* out = (float*)d_out;

    char* ws = (char*)d_ws;
    unsigned short* Ag  = (unsigned short*)(ws);              // 25.6 MB
    unsigned short* Xb  = (unsigned short*)(ws + 25600000);   // 12.8 MB
    unsigned char*  Xq  = (unsigned char*) (ws + 38400000);   // 6.4 MB (fp8 x)
    unsigned char*  T2q = (unsigned char*) (ws + 44800000);   // 3.2 MB (fp8 T2e)
    float* T2r    = (float*)(ws + 48000000);                  // 6.4 MB
    int*   rowptr = (int*)  (ws + 54400000);                  // 50001 ints
    uint2* epack8 = (uint2*)(ws + 54600064);                  // 9.63 MB
    unsigned int* spack = (unsigned int*)(ws + 64233856);     // 3.2 MB
    int* bin_counter = (int*)(ws + 67433856);                 // NBUCK ints
    unsigned short* Wp  = (unsigned short*)(ws + 67434880);   // 384*128 bf16
    unsigned short* Wp2 = (unsigned short*)(ws + 67533184);   // 128*96 bf16

    const int* esrc = ei;
    const int* edst = ei + NE;

    // --- zero bin counters (graph-capturable memset node) ---
    (void)hipMemsetAsync(bin_counter, 0, NBUCK * sizeof(int), stream);

    // --- Fused preprocessing: pass1 (LDS-sorted coalesced) + convx + wpacks ---
    k_prep<<<PREP_TOT, 256, 0, stream>>>(x, Xb, Xq, W1, r1, Wp, W2, r2, Wp2,
                                         esrc, edst, ea, bin_counter, epack8);

    // --- CSR pass 2 (counting sort, 1024 threads/block) ---
    k_pass2<<<NBUCK, 1024, 0, stream>>>(epack8, bin_counter, spack, rowptr);

    // --- Layer 1 aggregation (fp8 gather, grid-stride persistent waves) ---
    agg1<<<AGG_BLOCKS, 256, 0, stream>>>(rowptr, spack, Xq, Ag);

    // --- Fused GEMM1+GEMM2 ---
    gemm12_mfma<<<(NN + 63) / 64, 256, 0, stream>>>(Ag, Xb, Wp, b1, Wp2, b2,
                                                    T2q, T2r);

    // --- Layer 2 aggregation + finalize (grid-stride persistent waves) ---
    agg2_final<<<AGG_BLOCKS, 256, 0, stream>>>(rowptr, spack, T2q, T2r, out);
}